// Round 4
// baseline (139.870 us; speedup 1.0000x reference)
//
#include <hip/hip_runtime.h>
#include <hip/hip_bf16.h>
#include <math.h>

#define G 64
#define NNODE 256      // nodes per graph (= O)
#define D_IN 128
#define HDIM 64
#define HEADS 4
#define E_PER 8192
#define NUM_NODES (G * NNODE)
#define E_TOTAL (G * E_PER)
#define BN_EPS 1e-5f

__device__ __forceinline__ float lrelu02(float x) { return x > 0.f ? x : 0.2f * x; }
// pair-granularity (32B) XOR swizzle of the 16 quads in a 256B row
__device__ __forceinline__ int swz_quad(int row, int quad) {
    return (((quad >> 1) ^ (row & 7)) << 1) | (quad & 1);
}

// ======================= K0: CSR build (once per graph) ==========
__global__ __launch_bounds__(512) void csr_build(
    const int* __restrict__ eidx, unsigned short* __restrict__ ssrc_all,
    int* __restrict__ offv_all)
{
    int g = blockIdx.x;
    __shared__ unsigned short ssrcL[E_PER];   // 16 KB
    __shared__ int cnt[NNODE], offv[NNODE], cur[NNODE];
    __shared__ int wsum[8];
    int t = threadIdx.x;
    if (t < NNODE) cnt[t] = 0;
    __syncthreads();

    const int* srcp = eidx + (size_t)g * E_PER;
    const int* dstp = eidx + E_TOTAL + (size_t)g * E_PER;
    int base = g * NNODE;

    for (int e = t; e < E_PER; e += 512) atomicAdd(&cnt[dstp[e] - base], 1);
    __syncthreads();

    int vincl = (t < NNODE) ? cnt[t] : 0;
    #pragma unroll
    for (int d = 1; d < 64; d <<= 1) {
        int o = __shfl_up(vincl, d);
        if ((t & 63) >= d) vincl += o;
    }
    if (t < NNODE && (t & 63) == 63) wsum[t >> 6] = vincl;
    __syncthreads();
    if (t < NNODE) {
        int w = t >> 6;
        int add = 0;
        if (w > 0) add += wsum[0];
        if (w > 1) add += wsum[1];
        if (w > 2) add += wsum[2];
        int ex = vincl - cnt[t] + add;
        offv[t] = ex; cur[t] = ex;
    }
    __syncthreads();

    for (int e = t; e < E_PER; e += 512) {
        int s = srcp[e] - base, d = dstp[e] - base;
        int pos = atomicAdd(&cur[d], 1);
        ssrcL[pos] = (unsigned short)s;
    }
    __syncthreads();

    for (int i = t; i < E_PER / 4; i += 512)
        ((unsigned long long*)(ssrc_all + (size_t)g * E_PER))[i] =
            ((const unsigned long long*)ssrcL)[i];
    if (t < NNODE) offv_all[g * 257 + t] = offv[t];
    if (t == 0) offv_all[g * 257 + 256] = E_PER;
}

// ======================= K1: omics encoder =======================
__global__ __launch_bounds__(256) void enc_kernel(
    const float* __restrict__ omics, const float* __restrict__ w,
    const float* __restrict__ b, const float* __restrict__ rot,
    const float* __restrict__ gamma, const float* __restrict__ beta,
    const float* __restrict__ mean, const float* __restrict__ var,
    float* __restrict__ x)
{
    int o = blockIdx.x;
    __shared__ float Wl[D_IN * HDIM];       // 32 KB
    __shared__ float Om[G * 132];           // 33 KB
    int t = threadIdx.x;
    for (int i = t; i < D_IN * HDIM / 4; i += 256)
        ((float4*)Wl)[i] = ((const float4*)(w + (size_t)o * D_IN * HDIM))[i];
    for (int i = t; i < G * (D_IN / 4); i += 256) {
        int g = i >> 5, dq = i & 31;
        *((float4*)(Om + g * 132) + dq) =
            ((const float4*)(omics + ((size_t)g * NNODE + o) * D_IN))[dq];
    }
    __syncthreads();

    int w4 = t >> 6, l = t & 63;
    int cq = l & 15, gsub = l >> 4;
    int gbase = w4 * 4 + gsub;
    float4 acc[4];
    #pragma unroll
    for (int gi = 0; gi < 4; ++gi) acc[gi] = make_float4(0.f, 0.f, 0.f, 0.f);

    for (int d = 0; d < D_IN; ++d) {
        float4 wv = *(const float4*)&Wl[d * 64 + cq * 4];
        #pragma unroll
        for (int gi = 0; gi < 4; ++gi) {
            float ov = Om[(gi * 16 + gbase) * 132 + d];
            acc[gi].x = fmaf(ov, wv.x, acc[gi].x);
            acc[gi].y = fmaf(ov, wv.y, acc[gi].y);
            acc[gi].z = fmaf(ov, wv.z, acc[gi].z);
            acc[gi].w = fmaf(ov, wv.w, acc[gi].w);
        }
    }

    float4 bv = ((const float4*)b)[o * 16 + cq];
    float4 rv = ((const float4*)rot)[o * 16 + cq];
    float4 mv = ((const float4*)mean)[o * 16 + cq];
    float4 vv = ((const float4*)var)[o * 16 + cq];
    float4 gv = ((const float4*)gamma)[o * 16 + cq];
    float4 be = ((const float4*)beta)[o * 16 + cq];
    float4 sc, kk;
    sc.x = cosf(rv.x) + sinf(rv.x); sc.y = cosf(rv.y) + sinf(rv.y);
    sc.z = cosf(rv.z) + sinf(rv.z); sc.w = cosf(rv.w) + sinf(rv.w);
    kk.x = gv.x * rsqrtf(vv.x + BN_EPS); kk.y = gv.y * rsqrtf(vv.y + BN_EPS);
    kk.z = gv.z * rsqrtf(vv.z + BN_EPS); kk.w = gv.w * rsqrtf(vv.w + BN_EPS);

    #pragma unroll
    for (int gi = 0; gi < 4; ++gi) {
        int g = gi * 16 + gbase;
        float4 v;
        v.x = fmaxf((acc[gi].x + bv.x) * sc.x, 0.f);
        v.y = fmaxf((acc[gi].y + bv.y) * sc.y, 0.f);
        v.z = fmaxf((acc[gi].z + bv.z) * sc.z, 0.f);
        v.w = fmaxf((acc[gi].w + bv.w) * sc.w, 0.f);
        v.x = (v.x - mv.x) * kk.x + be.x;
        v.y = (v.y - mv.y) * kk.y + be.y;
        v.z = (v.z - mv.z) * kk.z + be.z;
        v.w = (v.w - mv.w) * kk.w + be.w;
        *(float4*)&x[((size_t)(g * NNODE + o)) * 64 + cq * 4] = v;
    }
}

// ======================= K2: GAT1 linear =========================
__global__ __launch_bounds__(256) void gat1_lin(
    const float* __restrict__ x, const float* __restrict__ W,
    const float* __restrict__ att_s, const float* __restrict__ att_d,
    float* __restrict__ h1, float* __restrict__ as1, float* __restrict__ ad1)
{
    int blk = blockIdx.x;
    __shared__ float Xl[64 * 65];
    __shared__ float Wl[64 * 256];
    int t = threadIdx.x;
    int node0 = blk * 64;
    for (int i = t; i < 64 * 64; i += 256) {
        int nl = i >> 6, k = i & 63;
        Xl[nl * 65 + k] = x[(size_t)node0 * HDIM + i];
    }
    for (int i = t; i < 64 * 256 / 4; i += 256)
        ((float4*)Wl)[i] = ((const float4*)W)[i];
    __syncthreads();

    int w = t >> 6, l = t & 63;
    int nsub = l >> 2, csel = l & 3;
    float4 acc[4][4];
    #pragma unroll
    for (int ni = 0; ni < 4; ++ni)
        #pragma unroll
        for (int cj = 0; cj < 4; ++cj) acc[ni][cj] = make_float4(0.f, 0.f, 0.f, 0.f);

    for (int k = 0; k < 64; ++k) {
        float4 wv[4];
        #pragma unroll
        for (int cj = 0; cj < 4; ++cj)
            wv[cj] = *(const float4*)&Wl[k * 256 + w * 64 + cj * 16 + csel * 4];
        #pragma unroll
        for (int ni = 0; ni < 4; ++ni) {
            float xv = Xl[(ni * 16 + nsub) * 65 + k];
            #pragma unroll
            for (int cj = 0; cj < 4; ++cj) {
                acc[ni][cj].x = fmaf(xv, wv[cj].x, acc[ni][cj].x);
                acc[ni][cj].y = fmaf(xv, wv[cj].y, acc[ni][cj].y);
                acc[ni][cj].z = fmaf(xv, wv[cj].z, acc[ni][cj].z);
                acc[ni][cj].w = fmaf(xv, wv[cj].w, acc[ni][cj].w);
            }
        }
    }

    float4 as_w[4], ad_w[4];
    #pragma unroll
    for (int cj = 0; cj < 4; ++cj) {
        as_w[cj] = ((const float4*)att_s)[w * 16 + cj * 4 + csel];
        ad_w[cj] = ((const float4*)att_d)[w * 16 + cj * 4 + csel];
    }
    #pragma unroll
    for (int ni = 0; ni < 4; ++ni) {
        int n = ni * 16 + nsub;
        float asv = 0.f, adv = 0.f;
        #pragma unroll
        for (int cj = 0; cj < 4; ++cj) {
            asv += acc[ni][cj].x * as_w[cj].x + acc[ni][cj].y * as_w[cj].y
                 + acc[ni][cj].z * as_w[cj].z + acc[ni][cj].w * as_w[cj].w;
            adv += acc[ni][cj].x * ad_w[cj].x + acc[ni][cj].y * ad_w[cj].y
                 + acc[ni][cj].z * ad_w[cj].z + acc[ni][cj].w * ad_w[cj].w;
            *(float4*)&h1[((size_t)(node0 + n) * HEADS + w) * 64 + cj * 16 + csel * 4]
                = acc[ni][cj];
        }
        asv += __shfl_xor(asv, 1); asv += __shfl_xor(asv, 2);
        adv += __shfl_xor(adv, 1); adv += __shfl_xor(adv, 2);
        if (csel == 0) {
            as1[(node0 + n) * HEADS + w] = asv;
            ad1[(node0 + n) * HEADS + w] = adv;
        }
    }
}

// ======================= K3: GAT1 edge gather ====================
// grid (G, HEADS), 512 thr. Prebuilt CSR; swizzled hl; on-the-fly alpha.
__global__ __launch_bounds__(512) void gat1_edge(
    const float* __restrict__ h1, const float* __restrict__ as1,
    const float* __restrict__ ad1, const unsigned short* __restrict__ ssrc_all,
    const int* __restrict__ offv_all, const float* __restrict__ bias1,
    float* __restrict__ x2)
{
    int g = blockIdx.x, head = blockIdx.y;
    __shared__ float hl[NNODE * 64];          // 64 KB, pair-swizzled rows
    __shared__ unsigned short ssrcL[E_PER];   // 16 KB
    __shared__ int offL[NNODE + 1];
    __shared__ float asl[NNODE], adl[NNODE], mtl[NNODE];
    __shared__ float wmax[8];
    int t = threadIdx.x;

    for (int i = t; i < NNODE * 16; i += 512) {
        int node = i >> 4, cq = i & 15;
        float4 v = ((const float4*)h1)[((size_t)(g * NNODE + node) * HEADS + head) * 16 + cq];
        ((float4*)hl)[node * 16 + swz_quad(node, cq)] = v;
    }
    for (int i = t; i < E_PER / 4; i += 512)
        ((unsigned long long*)ssrcL)[i] =
            ((const unsigned long long*)(ssrc_all + (size_t)g * E_PER))[i];
    if (t <= NNODE) offL[t] = offv_all[g * 257 + t];
    if (t < NNODE) {
        asl[t] = as1[(g * NNODE + t) * HEADS + head];
        adl[t] = ad1[(g * NNODE + t) * HEADS + head];
    }
    __syncthreads();

    {   // maxAS over 256 nodes
        float mv = (t < NNODE) ? asl[t] : -1e30f;
        #pragma unroll
        for (int d = 32; d; d >>= 1) mv = fmaxf(mv, __shfl_xor(mv, d));
        if ((t & 63) == 0) wmax[t >> 6] = mv;
    }
    __syncthreads();
    if (t < NNODE) {
        float M = fmaxf(fmaxf(wmax[0], wmax[1]), fmaxf(wmax[2], wmax[3]));
        mtl[t] = lrelu02(M + adl[t]);
    }
    __syncthreads();

    // gather: wave per dst-run; lane = (sub-edge 0..7, channel-pair q 0..7)
    int w = t >> 6, l = t & 63;
    int sub = l >> 3, q = l & 7;
    float4 bj0 = ((const float4*)bias1)[head * 16 + 2 * q];
    float4 bj1 = ((const float4*)bias1)[head * 16 + 2 * q + 1];
    for (int di = 0; di < 32; ++di) {
        int d = w * 32 + di;
        int rs = offL[d], deg = offL[d + 1] - rs;
        float adv = adl[d], mtv = mtl[d];
        float4 a0 = make_float4(0.f, 0.f, 0.f, 0.f);
        float4 a1 = make_float4(0.f, 0.f, 0.f, 0.f);
        float ss = 0.f;
        for (int k = 0; k < deg; k += 8) {
            int e = k + sub;
            int idx = rs + (e < deg ? e : 0);
            int s = ssrcL[idx];
            float av = __expf(lrelu02(asl[s] + adv) - mtv);
            av = (e < deg) ? av : 0.f;
            int pp = s * 16 + ((q ^ (s & 7)) << 1);
            float4 h0 = ((const float4*)hl)[pp];
            float4 h1v = ((const float4*)hl)[pp + 1];
            a0.x = fmaf(av, h0.x, a0.x); a0.y = fmaf(av, h0.y, a0.y);
            a0.z = fmaf(av, h0.z, a0.z); a0.w = fmaf(av, h0.w, a0.w);
            a1.x = fmaf(av, h1v.x, a1.x); a1.y = fmaf(av, h1v.y, a1.y);
            a1.z = fmaf(av, h1v.z, a1.z); a1.w = fmaf(av, h1v.w, a1.w);
            ss += av;
        }
        #pragma unroll
        for (int m = 8; m <= 32; m <<= 1) {
            a0.x += __shfl_xor(a0.x, m); a0.y += __shfl_xor(a0.y, m);
            a0.z += __shfl_xor(a0.z, m); a0.w += __shfl_xor(a0.w, m);
            a1.x += __shfl_xor(a1.x, m); a1.y += __shfl_xor(a1.y, m);
            a1.z += __shfl_xor(a1.z, m); a1.w += __shfl_xor(a1.w, m);
            ss += __shfl_xor(ss, m);
        }
        if (sub == 0) {
            float inv = 1.f / (ss + 1e-16f);
            float4 v0, v1;
            v0.x = a0.x * inv + bj0.x; v0.y = a0.y * inv + bj0.y;
            v0.z = a0.z * inv + bj0.z; v0.w = a0.w * inv + bj0.w;
            v1.x = a1.x * inv + bj1.x; v1.y = a1.y * inv + bj1.y;
            v1.z = a1.z * inv + bj1.z; v1.w = a1.w * inv + bj1.w;
            v0.x = v0.x > 0.f ? v0.x : expm1f(v0.x);
            v0.y = v0.y > 0.f ? v0.y : expm1f(v0.y);
            v0.z = v0.z > 0.f ? v0.z : expm1f(v0.z);
            v0.w = v0.w > 0.f ? v0.w : expm1f(v0.w);
            v1.x = v1.x > 0.f ? v1.x : expm1f(v1.x);
            v1.y = v1.y > 0.f ? v1.y : expm1f(v1.y);
            v1.z = v1.z > 0.f ? v1.z : expm1f(v1.z);
            v1.w = v1.w > 0.f ? v1.w : expm1f(v1.w);
            size_t ob = (size_t)(g * NNODE + d) * 256 + head * 64 + q * 8;
            *(float4*)&x2[ob] = v0;
            *(float4*)&x2[ob + 4] = v1;
        }
    }
}

// ======================= K4: GAT2 linear =========================
__global__ __launch_bounds__(256) void gat2_lin(
    const float* __restrict__ x2, const float* __restrict__ W,
    const float* __restrict__ att_s, const float* __restrict__ att_d,
    float* __restrict__ h2, float* __restrict__ as2, float* __restrict__ ad2)
{
    int blk = blockIdx.x;
    __shared__ float Xl[64 * 260];
    __shared__ float Wl[256 * 64];
    int t = threadIdx.x;
    int node0 = blk * 64;
    for (int i = t; i < 64 * 64; i += 256) {
        int nl = i >> 6, kq = i & 63;
        *((float4*)(Xl + nl * 260) + kq) =
            ((const float4*)(x2 + (size_t)(node0 + nl) * 256))[kq];
    }
    for (int i = t; i < 256 * 64 / 4; i += 256)
        ((float4*)Wl)[i] = ((const float4*)W)[i];
    __syncthreads();

    int w = t >> 6, l = t & 63;
    int cq = l & 15, nsub = l >> 4;
    float4 acc[4];
    #pragma unroll
    for (int ni = 0; ni < 4; ++ni) acc[ni] = make_float4(0.f, 0.f, 0.f, 0.f);

    for (int k0 = 0; k0 < 256; k0 += 4) {
        float4 wv[4];
        #pragma unroll
        for (int kk = 0; kk < 4; ++kk)
            wv[kk] = *(const float4*)&Wl[(k0 + kk) * 64 + cq * 4];
        #pragma unroll
        for (int ni = 0; ni < 4; ++ni) {
            float4 xq = *(const float4*)&Xl[(w * 16 + ni * 4 + nsub) * 260 + k0];
            acc[ni].x = fmaf(xq.x, wv[0].x, acc[ni].x);
            acc[ni].y = fmaf(xq.x, wv[0].y, acc[ni].y);
            acc[ni].z = fmaf(xq.x, wv[0].z, acc[ni].z);
            acc[ni].w = fmaf(xq.x, wv[0].w, acc[ni].w);
            acc[ni].x = fmaf(xq.y, wv[1].x, acc[ni].x);
            acc[ni].y = fmaf(xq.y, wv[1].y, acc[ni].y);
            acc[ni].z = fmaf(xq.y, wv[1].z, acc[ni].z);
            acc[ni].w = fmaf(xq.y, wv[1].w, acc[ni].w);
            acc[ni].x = fmaf(xq.z, wv[2].x, acc[ni].x);
            acc[ni].y = fmaf(xq.z, wv[2].y, acc[ni].y);
            acc[ni].z = fmaf(xq.z, wv[2].z, acc[ni].z);
            acc[ni].w = fmaf(xq.z, wv[2].w, acc[ni].w);
            acc[ni].x = fmaf(xq.w, wv[3].x, acc[ni].x);
            acc[ni].y = fmaf(xq.w, wv[3].y, acc[ni].y);
            acc[ni].z = fmaf(xq.w, wv[3].z, acc[ni].z);
            acc[ni].w = fmaf(xq.w, wv[3].w, acc[ni].w);
        }
    }

    float4 as_w = ((const float4*)att_s)[cq];
    float4 ad_w = ((const float4*)att_d)[cq];
    #pragma unroll
    for (int ni = 0; ni < 4; ++ni) {
        int n = w * 16 + ni * 4 + nsub;
        float asv = acc[ni].x * as_w.x + acc[ni].y * as_w.y
                  + acc[ni].z * as_w.z + acc[ni].w * as_w.w;
        float adv = acc[ni].x * ad_w.x + acc[ni].y * ad_w.y
                  + acc[ni].z * ad_w.z + acc[ni].w * ad_w.w;
        #pragma unroll
        for (int m = 1; m <= 8; m <<= 1) {
            asv += __shfl_xor(asv, m);
            adv += __shfl_xor(adv, m);
        }
        *(float4*)&h2[(size_t)(node0 + n) * 64 + cq * 4] = acc[ni];
        if (cq == 0) { as2[node0 + n] = asv; ad2[node0 + n] = adv; }
    }
}

// ======================= K5: GAT2 edge + partial pool ============
// grid (G, 4): quarter of dst nodes per block.
__global__ __launch_bounds__(512) void gat2_edge(
    const float* __restrict__ h2, const float* __restrict__ as2,
    const float* __restrict__ ad2, const unsigned short* __restrict__ ssrc_all,
    const int* __restrict__ offv_all, float* __restrict__ pl4)
{
    int g = blockIdx.x, qq = blockIdx.y;
    __shared__ float hl[NNODE * 64];
    __shared__ unsigned short ssrcL[E_PER];
    __shared__ int offL[NNODE + 1];
    __shared__ float asl[NNODE], adl[NNODE], mtl[NNODE];
    __shared__ float wmax[8];
    __shared__ float plq[8][64];
    int t = threadIdx.x;

    for (int i = t; i < NNODE * 16; i += 512) {
        int node = i >> 4, cq = i & 15;
        float4 v = ((const float4*)h2)[(size_t)g * NNODE * 16 + i];
        ((float4*)hl)[node * 16 + swz_quad(node, cq)] = v;
    }
    for (int i = t; i < E_PER / 4; i += 512)
        ((unsigned long long*)ssrcL)[i] =
            ((const unsigned long long*)(ssrc_all + (size_t)g * E_PER))[i];
    if (t <= NNODE) offL[t] = offv_all[g * 257 + t];
    if (t < NNODE) {
        asl[t] = as2[g * NNODE + t];
        adl[t] = ad2[g * NNODE + t];
    }
    __syncthreads();

    {
        float mv = (t < NNODE) ? asl[t] : -1e30f;
        #pragma unroll
        for (int d = 32; d; d >>= 1) mv = fmaxf(mv, __shfl_xor(mv, d));
        if ((t & 63) == 0) wmax[t >> 6] = mv;
    }
    __syncthreads();
    if (t < NNODE) {
        float M = fmaxf(fmaxf(wmax[0], wmax[1]), fmaxf(wmax[2], wmax[3]));
        mtl[t] = lrelu02(M + adl[t]);
    }
    __syncthreads();

    int w = t >> 6, l = t & 63;
    int sub = l >> 3, q = l & 7;
    float4 p0 = make_float4(0.f, 0.f, 0.f, 0.f);
    float4 p1 = make_float4(0.f, 0.f, 0.f, 0.f);
    for (int di = 0; di < 8; ++di) {
        int d = qq * 64 + w * 8 + di;
        int rs = offL[d], deg = offL[d + 1] - rs;
        float adv = adl[d], mtv = mtl[d];
        float4 a0 = make_float4(0.f, 0.f, 0.f, 0.f);
        float4 a1 = make_float4(0.f, 0.f, 0.f, 0.f);
        float ss = 0.f;
        for (int k = 0; k < deg; k += 8) {
            int e = k + sub;
            int idx = rs + (e < deg ? e : 0);
            int s = ssrcL[idx];
            float av = __expf(lrelu02(asl[s] + adv) - mtv);
            av = (e < deg) ? av : 0.f;
            int pp = s * 16 + ((q ^ (s & 7)) << 1);
            float4 h0 = ((const float4*)hl)[pp];
            float4 h1v = ((const float4*)hl)[pp + 1];
            a0.x = fmaf(av, h0.x, a0.x); a0.y = fmaf(av, h0.y, a0.y);
            a0.z = fmaf(av, h0.z, a0.z); a0.w = fmaf(av, h0.w, a0.w);
            a1.x = fmaf(av, h1v.x, a1.x); a1.y = fmaf(av, h1v.y, a1.y);
            a1.z = fmaf(av, h1v.z, a1.z); a1.w = fmaf(av, h1v.w, a1.w);
            ss += av;
        }
        #pragma unroll
        for (int m = 8; m <= 32; m <<= 1) {
            a0.x += __shfl_xor(a0.x, m); a0.y += __shfl_xor(a0.y, m);
            a0.z += __shfl_xor(a0.z, m); a0.w += __shfl_xor(a0.w, m);
            a1.x += __shfl_xor(a1.x, m); a1.y += __shfl_xor(a1.y, m);
            a1.z += __shfl_xor(a1.z, m); a1.w += __shfl_xor(a1.w, m);
            ss += __shfl_xor(ss, m);
        }
        float inv = 1.f / (ss + 1e-16f);
        p0.x = fmaf(a0.x, inv, p0.x); p0.y = fmaf(a0.y, inv, p0.y);
        p0.z = fmaf(a0.z, inv, p0.z); p0.w = fmaf(a0.w, inv, p0.w);
        p1.x = fmaf(a1.x, inv, p1.x); p1.y = fmaf(a1.y, inv, p1.y);
        p1.z = fmaf(a1.z, inv, p1.z); p1.w = fmaf(a1.w, inv, p1.w);
    }
    if (sub == 0) {
        *(float4*)&plq[w][q * 8] = p0;
        *(float4*)&plq[w][q * 8 + 4] = p1;
    }
    __syncthreads();
    if (t < 64) {
        float tot = 0.f;
        #pragma unroll
        for (int ww = 0; ww < 8; ++ww) tot += plq[ww][t];
        pl4[(g * 4 + qq) * 64 + t] = tot;
    }
}

// ======================= K6: pool-combine + classifier ===========
__global__ __launch_bounds__(64) void cls_kernel(
    const float* __restrict__ pl4, const float* __restrict__ bias2,
    const float* __restrict__ w1, const float* __restrict__ b1,
    const float* __restrict__ w2, const float* __restrict__ b2,
    float* __restrict__ outv, float* __restrict__ pooled)
{
    int g = blockIdx.x, c = threadIdx.x;
    float po = 0.f;
    #pragma unroll
    for (int q = 0; q < 4; ++q) po += pl4[(g * 4 + q) * 64 + c];
    po = po * (1.f / 256.f) + bias2[c];
    pooled[g * 64 + c] = po;
    __shared__ float poL[64];
    poL[c] = po;
    __syncthreads();
    float acc = b1[c];
    for (int k = 0; k < 64; ++k) acc = fmaf(poL[k], w1[k * 64 + c], acc);
    acc = fmaxf(acc, 0.f);
    float contrib = acc * w2[c];
    #pragma unroll
    for (int d = 32; d; d >>= 1) contrib += __shfl_xor(contrib, d);
    if (c == 0) outv[g] = 1.f / (1.f + __expf(-contrib));
}

extern "C" void kernel_launch(void* const* d_in, const int* in_sizes, int n_in,
                              void* d_out, int out_size, void* d_ws, size_t ws_size,
                              hipStream_t stream) {
    const float* omics   = (const float*)d_in[0];
    const float* w_omics = (const float*)d_in[1];
    const float* b_omics = (const float*)d_in[2];
    const float* rot     = (const float*)d_in[3];
    const float* bn_g    = (const float*)d_in[4];
    const float* bn_b    = (const float*)d_in[5];
    const float* bn_m    = (const float*)d_in[6];
    const float* bn_v    = (const float*)d_in[7];
    const float* gat1_w  = (const float*)d_in[8];
    const float* att_s1  = (const float*)d_in[9];
    const float* att_d1  = (const float*)d_in[10];
    const float* bias1   = (const float*)d_in[11];
    const float* gat2_w  = (const float*)d_in[12];
    const float* att_s2  = (const float*)d_in[13];
    const float* att_d2  = (const float*)d_in[14];
    const float* bias2   = (const float*)d_in[15];
    const float* cls_w1  = (const float*)d_in[16];
    const float* cls_b1  = (const float*)d_in[17];
    const float* cls_w2  = (const float*)d_in[18];
    const float* cls_b2  = (const float*)d_in[19];
    const int*   eidx    = (const int*)d_in[20];

    float* ws = (float*)d_ws;
    size_t o_x    = 0;
    size_t o_h1   = o_x  + (size_t)NUM_NODES * HDIM;
    size_t o_as1  = o_h1 + (size_t)NUM_NODES * HEADS * 64;
    size_t o_ad1  = o_as1 + (size_t)NUM_NODES * HEADS;
    size_t o_x2   = o_ad1 + (size_t)NUM_NODES * HEADS;
    size_t o_h2   = o_x2 + (size_t)NUM_NODES * HEADS * 64;
    size_t o_as2  = o_h2 + (size_t)NUM_NODES * 64;
    size_t o_ad2  = o_as2 + (size_t)NUM_NODES;
    size_t o_pl4  = o_ad2 + (size_t)NUM_NODES;
    size_t o_ssrc = o_pl4 + (size_t)G * 4 * 64;
    size_t o_offv = o_ssrc + (size_t)E_TOTAL / 2;   // u16 array in f32 units

    float* x   = ws + o_x;
    float* h1  = ws + o_h1;
    float* as1 = ws + o_as1;
    float* ad1 = ws + o_ad1;
    float* x2  = ws + o_x2;
    float* h2  = ws + o_h2;
    float* as2 = ws + o_as2;
    float* ad2 = ws + o_ad2;
    float* pl4 = ws + o_pl4;
    unsigned short* ssrc_ws = (unsigned short*)(ws + o_ssrc);
    int* offv_ws = (int*)(ws + o_offv);

    float* outv   = (float*)d_out;        // [64]
    float* pooled = (float*)d_out + G;    // [64*64]

    csr_build<<<G, 512, 0, stream>>>(eidx, ssrc_ws, offv_ws);
    enc_kernel<<<256, 256, 0, stream>>>(omics, w_omics, b_omics, rot,
                                        bn_g, bn_b, bn_m, bn_v, x);
    gat1_lin<<<256, 256, 0, stream>>>(x, gat1_w, att_s1, att_d1, h1, as1, ad1);
    gat1_edge<<<dim3(G, HEADS), 512, 0, stream>>>(h1, as1, ad1, ssrc_ws, offv_ws,
                                                  bias1, x2);
    gat2_lin<<<256, 256, 0, stream>>>(x2, gat2_w, att_s2, att_d2, h2, as2, ad2);
    gat2_edge<<<dim3(G, 4), 512, 0, stream>>>(h2, as2, ad2, ssrc_ws, offv_ws, pl4);
    cls_kernel<<<G, 64, 0, stream>>>(pl4, bias2, cls_w1, cls_b1, cls_w2, cls_b2,
                                     outv, pooled);
}

// Round 5
// 131.407 us; speedup vs baseline: 1.0644x; 1.0644x over previous
//
#include <hip/hip_runtime.h>
#include <hip/hip_bf16.h>
#include <math.h>

#define G 64
#define NNODE 256      // nodes per graph (= O)
#define D_IN 128
#define HDIM 64
#define HEADS 4
#define E_PER 8192
#define NUM_NODES (G * NNODE)
#define E_TOTAL (G * E_PER)
#define BN_EPS 1e-5f

typedef __attribute__((ext_vector_type(8))) short bf16x8;
typedef __attribute__((ext_vector_type(4))) float f32x4;

__device__ __forceinline__ float lrelu02(float x) { return x > 0.f ? x : 0.2f * x; }
__device__ __forceinline__ unsigned short f2bf(float f) {
    unsigned u = __float_as_uint(f);
    return (unsigned short)((u + 0x7FFFu + ((u >> 16) & 1u)) >> 16);
}

// ======================= K1: omics encoder =======================
__global__ __launch_bounds__(256) void enc_kernel(
    const float* __restrict__ omics, const float* __restrict__ w,
    const float* __restrict__ b, const float* __restrict__ rot,
    const float* __restrict__ gamma, const float* __restrict__ beta,
    const float* __restrict__ mean, const float* __restrict__ var,
    float* __restrict__ x)
{
    int o = blockIdx.x;
    __shared__ float Wl[D_IN * HDIM];       // 32 KB
    __shared__ float Om[G * 132];           // 33 KB
    int t = threadIdx.x;
    for (int i = t; i < D_IN * HDIM / 4; i += 256)
        ((float4*)Wl)[i] = ((const float4*)(w + (size_t)o * D_IN * HDIM))[i];
    for (int i = t; i < G * (D_IN / 4); i += 256) {
        int g = i >> 5, dq = i & 31;
        *((float4*)(Om + g * 132) + dq) =
            ((const float4*)(omics + ((size_t)g * NNODE + o) * D_IN))[dq];
    }
    __syncthreads();

    int w4 = t >> 6, l = t & 63;
    int cq = l & 15, gsub = l >> 4;
    int gbase = w4 * 4 + gsub;
    float4 acc[4];
    #pragma unroll
    for (int gi = 0; gi < 4; ++gi) acc[gi] = make_float4(0.f, 0.f, 0.f, 0.f);

    for (int d = 0; d < D_IN; ++d) {
        float4 wv = *(const float4*)&Wl[d * 64 + cq * 4];
        #pragma unroll
        for (int gi = 0; gi < 4; ++gi) {
            float ov = Om[(gi * 16 + gbase) * 132 + d];
            acc[gi].x = fmaf(ov, wv.x, acc[gi].x);
            acc[gi].y = fmaf(ov, wv.y, acc[gi].y);
            acc[gi].z = fmaf(ov, wv.z, acc[gi].z);
            acc[gi].w = fmaf(ov, wv.w, acc[gi].w);
        }
    }

    float4 bv = ((const float4*)b)[o * 16 + cq];
    float4 rv = ((const float4*)rot)[o * 16 + cq];
    float4 mv = ((const float4*)mean)[o * 16 + cq];
    float4 vv = ((const float4*)var)[o * 16 + cq];
    float4 gv = ((const float4*)gamma)[o * 16 + cq];
    float4 be = ((const float4*)beta)[o * 16 + cq];
    float4 sc, kk;
    sc.x = cosf(rv.x) + sinf(rv.x); sc.y = cosf(rv.y) + sinf(rv.y);
    sc.z = cosf(rv.z) + sinf(rv.z); sc.w = cosf(rv.w) + sinf(rv.w);
    kk.x = gv.x * rsqrtf(vv.x + BN_EPS); kk.y = gv.y * rsqrtf(vv.y + BN_EPS);
    kk.z = gv.z * rsqrtf(vv.z + BN_EPS); kk.w = gv.w * rsqrtf(vv.w + BN_EPS);

    #pragma unroll
    for (int gi = 0; gi < 4; ++gi) {
        int g = gi * 16 + gbase;
        float4 v;
        v.x = fmaxf((acc[gi].x + bv.x) * sc.x, 0.f);
        v.y = fmaxf((acc[gi].y + bv.y) * sc.y, 0.f);
        v.z = fmaxf((acc[gi].z + bv.z) * sc.z, 0.f);
        v.w = fmaxf((acc[gi].w + bv.w) * sc.w, 0.f);
        v.x = (v.x - mv.x) * kk.x + be.x;
        v.y = (v.y - mv.y) * kk.y + be.y;
        v.z = (v.z - mv.z) * kk.z + be.z;
        v.w = (v.w - mv.w) * kk.w + be.w;
        *(float4*)&x[((size_t)(g * NNODE + o)) * 64 + cq * 4] = v;
    }
}

// ======================= K2: GAT1 linear =========================
__global__ __launch_bounds__(256) void gat1_lin(
    const float* __restrict__ x, const float* __restrict__ W,
    const float* __restrict__ att_s, const float* __restrict__ att_d,
    float* __restrict__ h1, float* __restrict__ as1, float* __restrict__ ad1)
{
    int blk = blockIdx.x;
    __shared__ float Xl[64 * 65];
    __shared__ float Wl[64 * 256];
    int t = threadIdx.x;
    int node0 = blk * 64;
    for (int i = t; i < 64 * 64; i += 256) {
        int nl = i >> 6, k = i & 63;
        Xl[nl * 65 + k] = x[(size_t)node0 * HDIM + i];
    }
    for (int i = t; i < 64 * 256 / 4; i += 256)
        ((float4*)Wl)[i] = ((const float4*)W)[i];
    __syncthreads();

    int w = t >> 6, l = t & 63;
    int nsub = l >> 2, csel = l & 3;
    float4 acc[4][4];
    #pragma unroll
    for (int ni = 0; ni < 4; ++ni)
        #pragma unroll
        for (int cj = 0; cj < 4; ++cj) acc[ni][cj] = make_float4(0.f, 0.f, 0.f, 0.f);

    for (int k = 0; k < 64; ++k) {
        float4 wv[4];
        #pragma unroll
        for (int cj = 0; cj < 4; ++cj)
            wv[cj] = *(const float4*)&Wl[k * 256 + w * 64 + cj * 16 + csel * 4];
        #pragma unroll
        for (int ni = 0; ni < 4; ++ni) {
            float xv = Xl[(ni * 16 + nsub) * 65 + k];
            #pragma unroll
            for (int cj = 0; cj < 4; ++cj) {
                acc[ni][cj].x = fmaf(xv, wv[cj].x, acc[ni][cj].x);
                acc[ni][cj].y = fmaf(xv, wv[cj].y, acc[ni][cj].y);
                acc[ni][cj].z = fmaf(xv, wv[cj].z, acc[ni][cj].z);
                acc[ni][cj].w = fmaf(xv, wv[cj].w, acc[ni][cj].w);
            }
        }
    }

    float4 as_w[4], ad_w[4];
    #pragma unroll
    for (int cj = 0; cj < 4; ++cj) {
        as_w[cj] = ((const float4*)att_s)[w * 16 + cj * 4 + csel];
        ad_w[cj] = ((const float4*)att_d)[w * 16 + cj * 4 + csel];
    }
    #pragma unroll
    for (int ni = 0; ni < 4; ++ni) {
        int n = ni * 16 + nsub;
        float asv = 0.f, adv = 0.f;
        #pragma unroll
        for (int cj = 0; cj < 4; ++cj) {
            asv += acc[ni][cj].x * as_w[cj].x + acc[ni][cj].y * as_w[cj].y
                 + acc[ni][cj].z * as_w[cj].z + acc[ni][cj].w * as_w[cj].w;
            adv += acc[ni][cj].x * ad_w[cj].x + acc[ni][cj].y * ad_w[cj].y
                 + acc[ni][cj].z * ad_w[cj].z + acc[ni][cj].w * ad_w[cj].w;
            *(float4*)&h1[((size_t)(node0 + n) * HEADS + w) * 64 + cj * 16 + csel * 4]
                = acc[ni][cj];
        }
        asv += __shfl_xor(asv, 1); asv += __shfl_xor(asv, 2);
        adv += __shfl_xor(adv, 1); adv += __shfl_xor(adv, 2);
        if (csel == 0) {
            as1[(node0 + n) * HEADS + w] = asv;
            ad1[(node0 + n) * HEADS + w] = adv;
        }
    }
}

// ======================= K3: GAT1 edge via dense MFMA ============
// grid (G, HEADS), 512 thr. out[256x64] = M[256x256] @ H[256x64] in bf16 MFMA,
// M built sparsely from edges per k-quarter (factorized exp, no per-elem exp).
__global__ __launch_bounds__(512) void gat1_edge_mfma(
    const float* __restrict__ h1, const float* __restrict__ as1,
    const float* __restrict__ ad1, const int* __restrict__ eidx,
    const float* __restrict__ bias1, float* __restrict__ x2)
{
    int g = blockIdx.x, head = blockIdx.y;
    __shared__ float Mf[NNODE * 64];            // 64 KB, quad-XOR (d&15)
    __shared__ unsigned short Mb[NNODE * 64];   // 32 KB bf16, quad-XOR (d&7)
    __shared__ unsigned short ht[64 * NNODE];   // 32 KB bf16 H^T, quad-XOR (c&31)
    __shared__ float asl[NNODE], adl[NNODE], u1[NNODE], u2[NNODE];
    __shared__ float v1[NNODE], v2[NNODE], den[NNODE];
    __shared__ float wred[8];
    int t = threadIdx.x;

    // ---- P0: vectors + maxAS + factorized exp tables ----
    float va = -1e30f, vd = 0.f;
    if (t < NNODE) {
        va = as1[(g * NNODE + t) * HEADS + head];
        vd = ad1[(g * NNODE + t) * HEADS + head];
        asl[t] = va; adl[t] = vd; den[t] = 0.f;
    }
    {
        float mv = va;
        #pragma unroll
        for (int d = 32; d; d >>= 1) mv = fmaxf(mv, __shfl_xor(mv, d));
        if ((t & 63) == 0) wred[t >> 6] = mv;
    }
    __syncthreads();
    if (t < NNODE) {
        float M = fmaxf(fmaxf(wred[0], wred[1]), fmaxf(wred[2], wred[3]));
        float mt = lrelu02(M + vd);
        v1[t] = __expf(vd - mt);
        v2[t] = __expf(0.2f * vd - mt);
        u1[t] = __expf(va);
        u2[t] = __expf(0.2f * va);
    }
    // ---- ht build: bf16 transpose of H, swizzled ----
    for (int i = t; i < NNODE * 16; i += 512) {
        int s = i >> 4, cq = i & 15;
        float4 hv = ((const float4*)h1)[((size_t)(g * NNODE + s) * HEADS + head) * 16 + cq];
        int c0 = cq * 4;
        ht[(c0 + 0) * 256 + (((s >> 3) ^ ((c0 + 0) & 31)) << 3) + (s & 7)] = f2bf(hv.x);
        ht[(c0 + 1) * 256 + (((s >> 3) ^ ((c0 + 1) & 31)) << 3) + (s & 7)] = f2bf(hv.y);
        ht[(c0 + 2) * 256 + (((s >> 3) ^ ((c0 + 2) & 31)) << 3) + (s & 7)] = f2bf(hv.z);
        ht[(c0 + 3) * 256 + (((s >> 3) ^ ((c0 + 3) & 31)) << 3) + (s & 7)] = f2bf(hv.w);
    }
    __syncthreads();

    const int* srcp = eidx + (size_t)g * E_PER;
    const int* dstp = eidx + E_TOTAL + (size_t)g * E_PER;
    int base = g * NNODE;
    int w = t >> 6, l = t & 63;
    int lrow = l & 15, lk = l >> 4;

    f32x4 acc[2][4];
    #pragma unroll
    for (int mt = 0; mt < 2; ++mt)
        #pragma unroll
        for (int nt = 0; nt < 4; ++nt) {
            f32x4 z = {0.f, 0.f, 0.f, 0.f};
            acc[mt][nt] = z;
        }

    for (int q = 0; q < 4; ++q) {
        // zero Mf
        float4 z4 = make_float4(0.f, 0.f, 0.f, 0.f);
        for (int i = t; i < NNODE * 16; i += 512) ((float4*)Mf)[i] = z4;
        __syncthreads();
        // scatter: edges with src in this k-quarter
        for (int e = t; e < E_PER; e += 512) {
            int s = srcp[e] - base, d = dstp[e] - base;
            if ((s >> 6) == q) {
                float zf = asl[s] + adl[d];
                float p = zf > 0.f ? u1[s] * v1[d] : u2[s] * v2[d];
                int kl = s & 63, qd = kl >> 2;
                atomicAdd(&Mf[d * 64 + ((qd ^ (d & 15)) << 2) + (kl & 3)], p);
            }
        }
        __syncthreads();
        // cvt f32->bf16 + row strip sums
        {
            int d = t >> 1, kh = t & 1;   // k-half of 32
            float dsum = 0.f;
            #pragma unroll
            for (int j = 0; j < 4; ++j) {
                int lq0 = kh * 8 + 2 * j, lq1 = lq0 + 1;
                float4 f0 = *(const float4*)&Mf[d * 64 + ((lq0 ^ (d & 15)) << 2)];
                float4 f1 = *(const float4*)&Mf[d * 64 + ((lq1 ^ (d & 15)) << 2)];
                dsum += (f0.x + f0.y) + (f0.z + f0.w) + (f1.x + f1.y) + (f1.z + f1.w);
                bf16x8 sv;
                sv[0] = (short)f2bf(f0.x); sv[1] = (short)f2bf(f0.y);
                sv[2] = (short)f2bf(f0.z); sv[3] = (short)f2bf(f0.w);
                sv[4] = (short)f2bf(f1.x); sv[5] = (short)f2bf(f1.y);
                sv[6] = (short)f2bf(f1.z); sv[7] = (short)f2bf(f1.w);
                int mq = kh * 4 + j;
                *(bf16x8*)&Mb[d * 64 + ((mq ^ (d & 7)) << 3)] = sv;
            }
            atomicAdd(&den[d], dsum);
        }
        __syncthreads();
        // MFMA: this quarter's K=64 (2 k-blocks of 32)
        #pragma unroll
        for (int kbl = 0; kbl < 2; ++kbl) {
            int d0 = w * 32 + lrow, d1 = d0 + 16;
            int qd = kbl * 4 + lk;
            bf16x8 a0 = *(const bf16x8*)&Mb[d0 * 64 + ((qd ^ (d0 & 7)) << 3)];
            bf16x8 a1 = *(const bf16x8*)&Mb[d1 * 64 + ((qd ^ (d1 & 7)) << 3)];
            int qs = q * 8 + kbl * 4 + lk;
            #pragma unroll
            for (int nt = 0; nt < 4; ++nt) {
                int c = nt * 16 + lrow;
                bf16x8 bv = *(const bf16x8*)&ht[c * 256 + ((qs ^ (c & 31)) << 3)];
                acc[0][nt] = __builtin_amdgcn_mfma_f32_16x16x32_bf16(a0, bv, acc[0][nt], 0, 0, 0);
                acc[1][nt] = __builtin_amdgcn_mfma_f32_16x16x32_bf16(a1, bv, acc[1][nt], 0, 0, 0);
            }
        }
        __syncthreads();
    }

    // ---- epilogue: /den + bias + ELU -> x2 ----
    #pragma unroll
    for (int mt = 0; mt < 2; ++mt) {
        #pragma unroll
        for (int r = 0; r < 4; ++r) {
            int d = w * 32 + mt * 16 + lk * 4 + r;
            float inv = 1.f / (den[d] + 1e-16f);
            #pragma unroll
            for (int nt = 0; nt < 4; ++nt) {
                int c = nt * 16 + lrow;
                float v = acc[mt][nt][r] * inv + bias1[head * 64 + c];
                v = v > 0.f ? v : expm1f(v);
                x2[(size_t)(g * NNODE + d) * 256 + head * 64 + c] = v;
            }
        }
    }
}

// ======================= K4: GAT2 linear =========================
__global__ __launch_bounds__(256) void gat2_lin(
    const float* __restrict__ x2, const float* __restrict__ W,
    const float* __restrict__ att_s, const float* __restrict__ att_d,
    float* __restrict__ h2, float* __restrict__ as2, float* __restrict__ ad2)
{
    int blk = blockIdx.x;
    __shared__ float Xl[64 * 260];
    __shared__ float Wl[256 * 64];
    int t = threadIdx.x;
    int node0 = blk * 64;
    for (int i = t; i < 64 * 64; i += 256) {
        int nl = i >> 6, kq = i & 63;
        *((float4*)(Xl + nl * 260) + kq) =
            ((const float4*)(x2 + (size_t)(node0 + nl) * 256))[kq];
    }
    for (int i = t; i < 256 * 64 / 4; i += 256)
        ((float4*)Wl)[i] = ((const float4*)W)[i];
    __syncthreads();

    int w = t >> 6, l = t & 63;
    int cq = l & 15, nsub = l >> 4;
    float4 acc[4];
    #pragma unroll
    for (int ni = 0; ni < 4; ++ni) acc[ni] = make_float4(0.f, 0.f, 0.f, 0.f);

    for (int k0 = 0; k0 < 256; k0 += 4) {
        float4 wv[4];
        #pragma unroll
        for (int kk = 0; kk < 4; ++kk)
            wv[kk] = *(const float4*)&Wl[(k0 + kk) * 64 + cq * 4];
        #pragma unroll
        for (int ni = 0; ni < 4; ++ni) {
            float4 xq = *(const float4*)&Xl[(w * 16 + ni * 4 + nsub) * 260 + k0];
            acc[ni].x = fmaf(xq.x, wv[0].x, acc[ni].x);
            acc[ni].y = fmaf(xq.x, wv[0].y, acc[ni].y);
            acc[ni].z = fmaf(xq.x, wv[0].z, acc[ni].z);
            acc[ni].w = fmaf(xq.x, wv[0].w, acc[ni].w);
            acc[ni].x = fmaf(xq.y, wv[1].x, acc[ni].x);
            acc[ni].y = fmaf(xq.y, wv[1].y, acc[ni].y);
            acc[ni].z = fmaf(xq.y, wv[1].z, acc[ni].z);
            acc[ni].w = fmaf(xq.y, wv[1].w, acc[ni].w);
            acc[ni].x = fmaf(xq.z, wv[2].x, acc[ni].x);
            acc[ni].y = fmaf(xq.z, wv[2].y, acc[ni].y);
            acc[ni].z = fmaf(xq.z, wv[2].z, acc[ni].z);
            acc[ni].w = fmaf(xq.z, wv[2].w, acc[ni].w);
            acc[ni].x = fmaf(xq.w, wv[3].x, acc[ni].x);
            acc[ni].y = fmaf(xq.w, wv[3].y, acc[ni].y);
            acc[ni].z = fmaf(xq.w, wv[3].z, acc[ni].z);
            acc[ni].w = fmaf(xq.w, wv[3].w, acc[ni].w);
        }
    }

    float4 as_w = ((const float4*)att_s)[cq];
    float4 ad_w = ((const float4*)att_d)[cq];
    #pragma unroll
    for (int ni = 0; ni < 4; ++ni) {
        int n = w * 16 + ni * 4 + nsub;
        float asv = acc[ni].x * as_w.x + acc[ni].y * as_w.y
                  + acc[ni].z * as_w.z + acc[ni].w * as_w.w;
        float adv = acc[ni].x * ad_w.x + acc[ni].y * ad_w.y
                  + acc[ni].z * ad_w.z + acc[ni].w * ad_w.w;
        #pragma unroll
        for (int m = 1; m <= 8; m <<= 1) {
            asv += __shfl_xor(asv, m);
            adv += __shfl_xor(adv, m);
        }
        *(float4*)&h2[(size_t)(node0 + n) * 64 + cq * 4] = acc[ni];
        if (cq == 0) { as2[node0 + n] = asv; ad2[node0 + n] = adv; }
    }
}

// ======================= K5: GAT2 edge via dense MFMA + pool =====
// grid (G, 2): each block handles 128 dst rows, fuses partial mean-pool.
__global__ __launch_bounds__(512) void gat2_edge_mfma(
    const float* __restrict__ h2, const float* __restrict__ as2,
    const float* __restrict__ ad2, const int* __restrict__ eidx,
    float* __restrict__ pl2)
{
    int g = blockIdx.x, by = blockIdx.y;
    int rb = by * 128;
    __shared__ float Mf[128 * 64];              // 32 KB
    __shared__ unsigned short Mb[128 * 64];     // 16 KB
    __shared__ unsigned short ht[64 * NNODE];   // 32 KB
    __shared__ float asl[NNODE], adl[NNODE], u1[NNODE], u2[NNODE];
    __shared__ float v1[NNODE], v2[NNODE], den[128];
    __shared__ float wred[8];
    __shared__ float plq[8][64];
    int t = threadIdx.x;

    float va = -1e30f, vd = 0.f;
    if (t < NNODE) {
        va = as2[g * NNODE + t];
        vd = ad2[g * NNODE + t];
        asl[t] = va; adl[t] = vd;
        if (t < 128) den[t] = 0.f;
    }
    {
        float mv = va;
        #pragma unroll
        for (int d = 32; d; d >>= 1) mv = fmaxf(mv, __shfl_xor(mv, d));
        if ((t & 63) == 0) wred[t >> 6] = mv;
    }
    __syncthreads();
    if (t < NNODE) {
        float M = fmaxf(fmaxf(wred[0], wred[1]), fmaxf(wred[2], wred[3]));
        float mt = lrelu02(M + vd);
        v1[t] = __expf(vd - mt);
        v2[t] = __expf(0.2f * vd - mt);
        u1[t] = __expf(va);
        u2[t] = __expf(0.2f * va);
    }
    for (int i = t; i < NNODE * 16; i += 512) {
        int s = i >> 4, cq = i & 15;
        float4 hv = ((const float4*)h2)[(size_t)(g * NNODE + s) * 16 + cq];
        int c0 = cq * 4;
        ht[(c0 + 0) * 256 + (((s >> 3) ^ ((c0 + 0) & 31)) << 3) + (s & 7)] = f2bf(hv.x);
        ht[(c0 + 1) * 256 + (((s >> 3) ^ ((c0 + 1) & 31)) << 3) + (s & 7)] = f2bf(hv.y);
        ht[(c0 + 2) * 256 + (((s >> 3) ^ ((c0 + 2) & 31)) << 3) + (s & 7)] = f2bf(hv.z);
        ht[(c0 + 3) * 256 + (((s >> 3) ^ ((c0 + 3) & 31)) << 3) + (s & 7)] = f2bf(hv.w);
    }
    __syncthreads();

    const int* srcp = eidx + (size_t)g * E_PER;
    const int* dstp = eidx + E_TOTAL + (size_t)g * E_PER;
    int base = g * NNODE;
    int w = t >> 6, l = t & 63;
    int lrow = l & 15, lk = l >> 4;

    f32x4 acc[4];
    #pragma unroll
    for (int nt = 0; nt < 4; ++nt) {
        f32x4 z = {0.f, 0.f, 0.f, 0.f};
        acc[nt] = z;
    }

    for (int q = 0; q < 4; ++q) {
        float4 z4 = make_float4(0.f, 0.f, 0.f, 0.f);
        for (int i = t; i < 128 * 16; i += 512) ((float4*)Mf)[i] = z4;
        __syncthreads();
        for (int e = t; e < E_PER; e += 512) {
            int s = srcp[e] - base, d = dstp[e] - base;
            if ((s >> 6) == q && (d >> 7) == by) {
                int dl = d & 127;
                float zf = asl[s] + adl[d];
                float p = zf > 0.f ? u1[s] * v1[d] : u2[s] * v2[d];
                int kl = s & 63, qd = kl >> 2;
                atomicAdd(&Mf[dl * 64 + ((qd ^ (dl & 15)) << 2) + (kl & 3)], p);
            }
        }
        __syncthreads();
        if (t < 256) {
            int dl = t >> 1, kh = t & 1;
            float dsum = 0.f;
            #pragma unroll
            for (int j = 0; j < 4; ++j) {
                int lq0 = kh * 8 + 2 * j, lq1 = lq0 + 1;
                float4 f0 = *(const float4*)&Mf[dl * 64 + ((lq0 ^ (dl & 15)) << 2)];
                float4 f1 = *(const float4*)&Mf[dl * 64 + ((lq1 ^ (dl & 15)) << 2)];
                dsum += (f0.x + f0.y) + (f0.z + f0.w) + (f1.x + f1.y) + (f1.z + f1.w);
                bf16x8 sv;
                sv[0] = (short)f2bf(f0.x); sv[1] = (short)f2bf(f0.y);
                sv[2] = (short)f2bf(f0.z); sv[3] = (short)f2bf(f0.w);
                sv[4] = (short)f2bf(f1.x); sv[5] = (short)f2bf(f1.y);
                sv[6] = (short)f2bf(f1.z); sv[7] = (short)f2bf(f1.w);
                int mq = kh * 4 + j;
                *(bf16x8*)&Mb[dl * 64 + ((mq ^ (dl & 7)) << 3)] = sv;
            }
            atomicAdd(&den[dl], dsum);
        }
        __syncthreads();
        #pragma unroll
        for (int kbl = 0; kbl < 2; ++kbl) {
            int dl0 = w * 16 + lrow;
            int qd = kbl * 4 + lk;
            bf16x8 a0 = *(const bf16x8*)&Mb[dl0 * 64 + ((qd ^ (dl0 & 7)) << 3)];
            int qs = q * 8 + kbl * 4 + lk;
            #pragma unroll
            for (int nt = 0; nt < 4; ++nt) {
                int c = nt * 16 + lrow;
                bf16x8 bv = *(const bf16x8*)&ht[c * 256 + ((qs ^ (c & 31)) << 3)];
                acc[nt] = __builtin_amdgcn_mfma_f32_16x16x32_bf16(a0, bv, acc[nt], 0, 0, 0);
            }
        }
        __syncthreads();
    }

    // ---- epilogue: /den, partial pool over this block's 128 rows ----
    float ps[4] = {0.f, 0.f, 0.f, 0.f};
    #pragma unroll
    for (int r = 0; r < 4; ++r) {
        int dl = w * 16 + lk * 4 + r;
        float inv = 1.f / (den[dl] + 1e-16f);
        #pragma unroll
        for (int nt = 0; nt < 4; ++nt) ps[nt] = fmaf(acc[nt][r], inv, ps[nt]);
    }
    #pragma unroll
    for (int nt = 0; nt < 4; ++nt) {
        ps[nt] += __shfl_xor(ps[nt], 16);
        ps[nt] += __shfl_xor(ps[nt], 32);
    }
    if (l < 16) {
        #pragma unroll
        for (int nt = 0; nt < 4; ++nt) plq[w][nt * 16 + l] = ps[nt];
    }
    __syncthreads();
    if (t < 64) {
        float tot = 0.f;
        #pragma unroll
        for (int ww = 0; ww < 8; ++ww) tot += plq[ww][t];
        pl2[(g * 2 + by) * 64 + t] = tot;
    }
}

// ======================= K6: pool-combine + classifier ===========
__global__ __launch_bounds__(64) void cls_kernel(
    const float* __restrict__ pl2, const float* __restrict__ bias2,
    const float* __restrict__ w1, const float* __restrict__ b1,
    const float* __restrict__ w2, const float* __restrict__ b2,
    float* __restrict__ outv, float* __restrict__ pooled)
{
    int g = blockIdx.x, c = threadIdx.x;
    float po = pl2[(g * 2) * 64 + c] + pl2[(g * 2 + 1) * 64 + c];
    po = po * (1.f / 256.f) + bias2[c];
    pooled[g * 64 + c] = po;
    __shared__ float poL[64];
    poL[c] = po;
    __syncthreads();
    float acc = b1[c];
    for (int k = 0; k < 64; ++k) acc = fmaf(poL[k], w1[k * 64 + c], acc);
    acc = fmaxf(acc, 0.f);
    float contrib = acc * w2[c];
    #pragma unroll
    for (int d = 32; d; d >>= 1) contrib += __shfl_xor(contrib, d);
    if (c == 0) outv[g] = 1.f / (1.f + __expf(-contrib));
}

extern "C" void kernel_launch(void* const* d_in, const int* in_sizes, int n_in,
                              void* d_out, int out_size, void* d_ws, size_t ws_size,
                              hipStream_t stream) {
    const float* omics   = (const float*)d_in[0];
    const float* w_omics = (const float*)d_in[1];
    const float* b_omics = (const float*)d_in[2];
    const float* rot     = (const float*)d_in[3];
    const float* bn_g    = (const float*)d_in[4];
    const float* bn_b    = (const float*)d_in[5];
    const float* bn_m    = (const float*)d_in[6];
    const float* bn_v    = (const float*)d_in[7];
    const float* gat1_w  = (const float*)d_in[8];
    const float* att_s1  = (const float*)d_in[9];
    const float* att_d1  = (const float*)d_in[10];
    const float* bias1   = (const float*)d_in[11];
    const float* gat2_w  = (const float*)d_in[12];
    const float* att_s2  = (const float*)d_in[13];
    const float* att_d2  = (const float*)d_in[14];
    const float* bias2   = (const float*)d_in[15];
    const float* cls_w1  = (const float*)d_in[16];
    const float* cls_b1  = (const float*)d_in[17];
    const float* cls_w2  = (const float*)d_in[18];
    const float* cls_b2  = (const float*)d_in[19];
    const int*   eidx    = (const int*)d_in[20];

    float* ws = (float*)d_ws;
    size_t o_x    = 0;
    size_t o_h1   = o_x  + (size_t)NUM_NODES * HDIM;
    size_t o_as1  = o_h1 + (size_t)NUM_NODES * HEADS * 64;
    size_t o_ad1  = o_as1 + (size_t)NUM_NODES * HEADS;
    size_t o_x2   = o_ad1 + (size_t)NUM_NODES * HEADS;
    size_t o_h2   = o_x2 + (size_t)NUM_NODES * HEADS * 64;
    size_t o_as2  = o_h2 + (size_t)NUM_NODES * 64;
    size_t o_ad2  = o_as2 + (size_t)NUM_NODES;
    size_t o_pl2  = o_ad2 + (size_t)NUM_NODES;

    float* x   = ws + o_x;
    float* h1  = ws + o_h1;
    float* as1 = ws + o_as1;
    float* ad1 = ws + o_ad1;
    float* x2  = ws + o_x2;
    float* h2  = ws + o_h2;
    float* as2 = ws + o_as2;
    float* ad2 = ws + o_ad2;
    float* pl2 = ws + o_pl2;

    float* outv   = (float*)d_out;        // [64]
    float* pooled = (float*)d_out + G;    // [64*64]

    enc_kernel<<<256, 256, 0, stream>>>(omics, w_omics, b_omics, rot,
                                        bn_g, bn_b, bn_m, bn_v, x);
    gat1_lin<<<256, 256, 0, stream>>>(x, gat1_w, att_s1, att_d1, h1, as1, ad1);
    gat1_edge_mfma<<<dim3(G, HEADS), 512, 0, stream>>>(h1, as1, ad1, eidx, bias1, x2);
    gat2_lin<<<256, 256, 0, stream>>>(x2, gat2_w, att_s2, att_d2, h2, as2, ad2);
    gat2_edge_mfma<<<dim3(G, 2), 512, 0, stream>>>(h2, as2, ad2, eidx, pl2);
    cls_kernel<<<G, 64, 0, stream>>>(pl2, bias2, cls_w1, cls_b1, cls_w2, cls_b2,
                                     outv, pooled);
}